// Round 1
// baseline (1222.031 us; speedup 1.0000x reference)
//
#include <hip/hip_runtime.h>
#include <hip/hip_fp16.h>

typedef __attribute__((ext_vector_type(8))) _Float16 half8;
typedef __attribute__((ext_vector_type(4))) float float4a;

// LDS layout (bytes), total 163840:
//  Ksh  f16 [256 m][64 a]   @ 0       (32 KB)  K hi, swizzled rows of 128B
//  Ksl  f16 [256 m][64 a]   @ 32768   (32 KB)  K lo
//  VsT  f16 [64 a][256 m]   @ 65536   (32 KB)  V^T, swizzled rows of 512B
//  Qth  f16 [64 r][64 a]    @ 98304   ( 8 KB)  | phase A overlay: Xt f32 [256][8]
//  Qtl  f16 [64 r][64 a]    @ 106496  ( 8 KB)  | phase A overlay: Wt f32 [3][8][64]
//  Pt   f16 [64 r][256 m]   @ 114688  (32 KB)
//  PVt  f32 [64 r][64 a]    @ 147456  (16 KB)  | softmax red1/red2 overlay (2 KB)
#define OFF_KSH 0
#define OFF_KSL 32768
#define OFF_VST 65536
#define OFF_QTH 98304
#define OFF_QTL 106496
#define OFF_PT  114688
#define OFF_PVT 147456
#define OFF_RED1 147456
#define OFF_RED2 148480
#define OFF_XT  98304
#define OFF_WT  106496
#define LDS_BYTES 163840

// byte offset into a [r][64 f16] tile (128B rows), granule-XOR swizzled
__device__ __forceinline__ int swz128(int r, int c) {
    return (r << 7) + ((((c >> 3) ^ r) & 7) << 4) + ((c & 7) << 1);
}
// byte offset into a [r][256 f16] tile (512B rows), granule-XOR swizzled
__device__ __forceinline__ int swz512(int r, int c) {
    return (r << 9) + (((((c >> 3) ^ (r & 7))) & 31) << 4) + ((c & 7) << 1);
}

extern "C" __global__ void __launch_bounds__(1024)
va_fused(const float* __restrict__ Y,
         const float* __restrict__ Wq, const float* __restrict__ Wk,
         const float* __restrict__ Wv,
         const float* __restrict__ bq, const float* __restrict__ bk,
         const float* __restrict__ bv,
         const float* __restrict__ gama,
         const float* __restrict__ fcw, const float* __restrict__ fcb,
         float* __restrict__ out)
{
    extern __shared__ char smem[];
    const int tid  = (int)threadIdx.x;
    const int w    = tid >> 6;   // wave 0..15
    const int lane = tid & 63;

    const int blk = (int)blockIdx.x;
    const int b = blk & 15;
    const int l = blk >> 4;

    const size_t base = (size_t)b * (256u * 16384u) + (size_t)l * 256u;
    const float* __restrict__ Yb = Y + base;
    float* __restrict__ Ob = out + base;
    const float* __restrict__ Wql = Wq + l * 16384;
    const float* __restrict__ Wkl = Wk + l * 16384;
    const float* __restrict__ Wvl = Wv + l * 16384;

    float* Xt = (float*)(smem + OFF_XT);
    float* Wt = (float*)(smem + OFF_WT);

    // ---------------- Phase A: QKV projection (fp32 VALU) ----------------
    // thread (w,lane) computes rows r = i*64 + h*16 + w, output col a = lane
    float qa[4][4], ka[4][4], vaa[4][4];
    #pragma unroll
    for (int i = 0; i < 4; ++i)
        #pragma unroll
        for (int h = 0; h < 4; ++h) { qa[i][h] = 0.f; ka[i][h] = 0.f; vaa[i][h] = 0.f; }

    const int xrow = tid >> 2;
    const int xc2  = (tid & 3) * 2;
    const float* xsrc  = Yb + (size_t)xrow * 16384 + xc2;
    const float* wsrc0 = (tid < 512 ? Wql : Wkl) + (tid & 511);
    const float* wsrc1 = Wvl + tid;  // valid for tid < 512

    float2 xr = *(const float2*)xsrc;
    float w0r = *wsrc0;
    float w1r = (tid < 512) ? *wsrc1 : 0.0f;

    #pragma unroll 1
    for (int ct = 0; ct < 32; ++ct) {
        *(float2*)&Xt[xrow * 8 + xc2] = xr;
        Wt[tid] = w0r;
        if (tid < 512) Wt[1024 + tid] = w1r;
        __syncthreads();
        if (ct < 31) {  // prefetch next tile while computing this one
            xr  = *(const float2*)(xsrc + (ct + 1) * 8);
            w0r = wsrc0[(ct + 1) * 512];
            if (tid < 512) w1r = wsrc1[(ct + 1) * 512];
        }
        float wqr[8], wkr[8], wvr[8];
        #pragma unroll
        for (int c = 0; c < 8; ++c) {
            wqr[c] = Wt[c * 64 + lane];
            wkr[c] = Wt[512 + c * 64 + lane];
            wvr[c] = Wt[1024 + c * 64 + lane];
        }
        #pragma unroll
        for (int i = 0; i < 4; ++i) {
            #pragma unroll
            for (int h = 0; h < 4; ++h) {
                const int r = i * 64 + h * 16 + w;
                float x[8];
                *(float4a*)&x[0] = *(const float4a*)&Xt[r * 8];
                *(float4a*)&x[4] = *(const float4a*)&Xt[r * 8 + 4];
                #pragma unroll
                for (int c = 0; c < 8; ++c) {
                    qa[i][h]  = fmaf(x[c], wqr[c], qa[i][h]);
                    ka[i][h]  = fmaf(x[c], wkr[c], ka[i][h]);
                    vaa[i][h] = fmaf(x[c], wvr[c], vaa[i][h]);
                }
            }
        }
        __syncthreads();
    }

    // epilogue: K (hi/lo split) and V (single f16) into LDS; Q stays in regs
    {
        const float kbv = bk[lane];
        const float vbv = bv[lane];
        #pragma unroll
        for (int i = 0; i < 4; ++i) {
            #pragma unroll
            for (int h = 0; h < 4; ++h) {
                const int r = i * 64 + h * 16 + w;
                const float kv = ka[i][h] + kbv;
                const __half kh = __float2half_rn(kv);
                const __half kl = __float2half_rn(kv - __half2float(kh));
                *(__half*)(smem + OFF_KSH + swz128(r, lane)) = kh;
                *(__half*)(smem + OFF_KSL + swz128(r, lane)) = kl;
                *(__half*)(smem + OFF_VST + swz512(lane, r)) =
                    __float2half_rn(vaa[i][h] + vbv);
            }
        }
    }

    // ---------------- Phase B: 4 chunks of 64 rows ----------------
    const float qbv = bq[lane];
    const float gv  = gama[0];
    const float4a fcb4 = *(const float4a*)&fcb[lane * 4];
    const int l15 = lane & 15;
    const int kg  = lane >> 4;
    const int rt  = w & 3;    // S: row-tile   (rows 16*rt .. +15, chunk-local)
    const int mq  = w >> 2;   // S: m-quarter  (m 64*mq .. +63)
    const int rt2 = w >> 2;   // PV: row-tile
    const int at  = w & 3;    // PV: a-tile
    float* red1 = (float*)(smem + OFF_RED1);
    float* red2 = (float*)(smem + OFF_RED2);
    float* PVt  = (float*)(smem + OFF_PVT);

    #pragma unroll
    for (int ci = 0; ci < 4; ++ci) {
        // 1. Q chunk -> LDS (f16 hi/lo, swizzled)
        #pragma unroll
        for (int h = 0; h < 4; ++h) {
            const int j = h * 16 + w;
            const float qv = qa[ci][h] + qbv;
            const __half qh = __float2half_rn(qv);
            const __half ql = __float2half_rn(qv - __half2float(qh));
            *(__half*)(smem + OFF_QTH + swz128(j, lane)) = qh;
            *(__half*)(smem + OFF_QTL + swz128(j, lane)) = ql;
        }
        __syncthreads();

        // 2. S = Q K^T, 3-term split-f16 MFMA (fp32-class precision)
        float4a sacc[4];
        #pragma unroll
        for (int mt = 0; mt < 4; ++mt) sacc[mt] = (float4a)0.0f;
        const int arow = rt * 16 + l15;
        #pragma unroll
        for (int ks = 0; ks < 2; ++ks) {
            const int a0 = ks * 32 + kg * 8;
            const half8 ah = *(const half8*)(smem + OFF_QTH + swz128(arow, a0));
            const half8 al = *(const half8*)(smem + OFF_QTL + swz128(arow, a0));
            #pragma unroll
            for (int mt = 0; mt < 4; ++mt) {
                const int mcol = mq * 64 + mt * 16 + l15;
                const half8 bh = *(const half8*)(smem + OFF_KSH + swz128(mcol, a0));
                const half8 bl = *(const half8*)(smem + OFF_KSL + swz128(mcol, a0));
                sacc[mt] = __builtin_amdgcn_mfma_f32_16x16x32_f16(ah, bh, sacc[mt], 0, 0, 0);
                sacc[mt] = __builtin_amdgcn_mfma_f32_16x16x32_f16(ah, bl, sacc[mt], 0, 0, 0);
                sacc[mt] = __builtin_amdgcn_mfma_f32_16x16x32_f16(al, bh, sacc[mt], 0, 0, 0);
            }
        }

        // 3. softmax over m (rows rloc = rt*16 + kg*4 + jj; wave holds 64 m, 4 waves/row)
        float gmax[4];
        #pragma unroll
        for (int jj = 0; jj < 4; ++jj) {
            float m0 = fmaxf(fmaxf(sacc[0][jj], sacc[1][jj]),
                             fmaxf(sacc[2][jj], sacc[3][jj]));
            m0 = fmaxf(m0, __shfl_xor(m0, 1));
            m0 = fmaxf(m0, __shfl_xor(m0, 2));
            m0 = fmaxf(m0, __shfl_xor(m0, 4));
            m0 = fmaxf(m0, __shfl_xor(m0, 8));
            if (l15 == 0) red1[(rt * 16 + kg * 4 + jj) * 4 + mq] = m0;
        }
        __syncthreads();
        #pragma unroll
        for (int jj = 0; jj < 4; ++jj) {
            const float4a rm = *(const float4a*)&red1[(rt * 16 + kg * 4 + jj) * 4];
            gmax[jj] = fmaxf(fmaxf(rm[0], rm[1]), fmaxf(rm[2], rm[3]));
        }
        #pragma unroll
        for (int mt = 0; mt < 4; ++mt)
            #pragma unroll
            for (int jj = 0; jj < 4; ++jj)
                sacc[mt][jj] = __expf(sacc[mt][jj] - gmax[jj]);
        #pragma unroll
        for (int jj = 0; jj < 4; ++jj) {
            float s0 = sacc[0][jj] + sacc[1][jj] + sacc[2][jj] + sacc[3][jj];
            s0 += __shfl_xor(s0, 1);
            s0 += __shfl_xor(s0, 2);
            s0 += __shfl_xor(s0, 4);
            s0 += __shfl_xor(s0, 8);
            if (l15 == 0) red2[(rt * 16 + kg * 4 + jj) * 4 + mq] = s0;
        }
        __syncthreads();
        #pragma unroll
        for (int jj = 0; jj < 4; ++jj) {
            const float4a rs = *(const float4a*)&red2[(rt * 16 + kg * 4 + jj) * 4];
            const float inv = 1.0f / (rs[0] + rs[1] + rs[2] + rs[3]);
            const int rloc = rt * 16 + kg * 4 + jj;
            #pragma unroll
            for (int mt = 0; mt < 4; ++mt) {
                const int mcol = mq * 64 + mt * 16 + l15;
                *(__half*)(smem + OFF_PT + swz512(rloc, mcol)) =
                    __float2half_rn(sacc[mt][jj] * inv);
            }
        }
        __syncthreads();

        // 4. PV = P * V, single f16 MFMA (P in [0,1], V single f16 - precision ok)
        float4a pacc = (float4a)0.0f;
        #pragma unroll
        for (int ks = 0; ks < 8; ++ks) {
            const int mk = ks * 32 + kg * 8;
            const half8 pa = *(const half8*)(smem + OFF_PT  + swz512(rt2 * 16 + l15, mk));
            const half8 vb = *(const half8*)(smem + OFF_VST + swz512(at  * 16 + l15, mk));
            pacc = __builtin_amdgcn_mfma_f32_16x16x32_f16(pa, vb, pacc, 0, 0, 0);
        }
        #pragma unroll
        for (int jj = 0; jj < 4; ++jj)
            PVt[(rt2 * 16 + kg * 4 + jj) * 64 + at * 16 + l15] = pacc[jj];
        __syncthreads();

        // 5. fc (fp32 VALU, f32 weights from global/L2) + gated residual + store
        float o[4][4];
        #pragma unroll
        for (int rr = 0; rr < 4; ++rr)
            #pragma unroll
            for (int cc = 0; cc < 4; ++cc) o[rr][cc] = 0.0f;
        #pragma unroll 4
        for (int a4 = 0; a4 < 16; ++a4) {
            float4a pv[4];
            #pragma unroll
            for (int rr = 0; rr < 4; ++rr)
                pv[rr] = *(const float4a*)&PVt[(w * 4 + rr) * 64 + a4 * 4];
            #pragma unroll
            for (int cc = 0; cc < 4; ++cc) {
                const float4a wc = *(const float4a*)&fcw[(lane * 4 + cc) * 64 + a4 * 4];
                #pragma unroll
                for (int rr = 0; rr < 4; ++rr) {
                    o[rr][cc] = fmaf(pv[rr][0], wc[0], o[rr][cc]);
                    o[rr][cc] = fmaf(pv[rr][1], wc[1], o[rr][cc]);
                    o[rr][cc] = fmaf(pv[rr][2], wc[2], o[rr][cc]);
                    o[rr][cc] = fmaf(pv[rr][3], wc[3], o[rr][cc]);
                }
            }
        }
        #pragma unroll
        for (int rr = 0; rr < 4; ++rr) {
            const int rg = ci * 64 + w * 4 + rr;
            const float4a x4 = *(const float4a*)(Yb + (size_t)rg * 16384 + lane * 4);
            float4a r4;
            #pragma unroll
            for (int cc = 0; cc < 4; ++cc)
                r4[cc] = x4[cc] + gv * (o[rr][cc] + fcb4[cc]);
            *(float4a*)(Ob + (size_t)rg * 16384 + lane * 4) = r4;
        }
    }
}

extern "C" void kernel_launch(void* const* d_in, const int* in_sizes, int n_in,
                              void* d_out, int out_size, void* d_ws, size_t ws_size,
                              hipStream_t stream) {
    (void)in_sizes; (void)n_in; (void)d_ws; (void)ws_size; (void)out_size;
    const float* Y    = (const float*)d_in[0];
    const float* Wq   = (const float*)d_in[1];
    const float* Wk   = (const float*)d_in[2];
    const float* Wv   = (const float*)d_in[3];
    const float* bq   = (const float*)d_in[4];
    const float* bk   = (const float*)d_in[5];
    const float* bv   = (const float*)d_in[6];
    const float* gama = (const float*)d_in[7];
    const float* fcw  = (const float*)d_in[8];
    const float* fcb  = (const float*)d_in[9];
    float* outp = (float*)d_out;

    // allow 160 KB dynamic LDS (idempotent, capture-safe: not a stream op)
    (void)hipFuncSetAttribute((const void*)va_fused,
                              hipFuncAttributeMaxDynamicSharedMemorySize, LDS_BYTES);

    va_fused<<<dim3(1024), dim3(1024), LDS_BYTES, stream>>>(
        Y, Wq, Wk, Wv, bq, bk, bv, gama, fcw, fcb, outp);
}